// Round 13
// baseline (219.658 us; speedup 1.0000x reference)
//
#include <hip/hip_runtime.h>
#include <hip/hip_bf16.h>

// MaskedGAT: N=6144, HID=128, HEADS=4, sparse (deg ~33) formulation.
// R10..R13: runtime dtype detection, corrected discriminator. bf16 == top
// half of f32, so an f32-exponent test cannot distinguish stagings; instead vote
// on word bits [14:7]: low-bf16 exponent (concentrated [110,135] for N(0,1)) if
// bf16-staged, uniform mid-mantissa if f32-staged (~10% in range). Vote 32/64.
// Evidence for f32 staging: R0+R8 NaN THROUGH the denom>0 guard — impossible in
// the bf16 world (audited), explained by f32-as-bf16 misread (1/256 of low
// halves have exp=0xFF -> NaN floods q/k/v via MFMA).
// Edge int64/int32 detection retained. All branches device-side (graph-safe).

#define N_NODES 6144
#define HIDC 128
#define QKV_N 512                 // HID*HEADS
#define MASK_WPR 192              // 6144/32 words per row

typedef __bf16 bf16;
typedef __attribute__((ext_vector_type(8))) __bf16 bf16x8;
typedef __attribute__((ext_vector_type(4))) float f32x4;

// fflag=1 iff floats staged f32. One wave reads H's first 64 32-bit words and
// votes on bits [14:7]: low-bf16 exponent (always ~[110,135] for N(0,1) data)
// vs f32 mid-mantissa (uniform, ~10% in range). >=32 in-range -> bf16 staging.
__global__ void k_detect_f(const unsigned* __restrict__ Hw, int* __restrict__ fflag) {
    int lane = threadIdx.x;
    unsigned w = Hw[lane];
    int el = (w >> 7) & 0xFF;
    unsigned long long b = __ballot(el >= 110 && el <= 135);
    if (lane == 0) *fflag = (__popcll(b) >= 32) ? 0 : 1;
}

// eflag=1 iff edges staged int64 (odd 32-bit words all zero; node ids < 6144).
// For int32 staging those words are random node ids: P(all 64 zero) ~ 6144^-64.
__global__ void k_detect_e(const int* __restrict__ e32, int* __restrict__ eflag) {
    int lane = threadIdx.x;
    unsigned long long b = __ballot(e32[2 * lane + 1] == 0);
    if (lane == 0) *eflag = (b == ~0ull) ? 1 : 0;
}

__global__ __launch_bounds__(256) void k_cast(const void* __restrict__ src,
                                              bf16* __restrict__ dst, int n,
                                              const int* __restrict__ fflag) {
    int i = blockIdx.x * 256 + threadIdx.x;
    if (i >= n) return;
    if (*fflag) dst[i] = (bf16)((const float*)src)[i];
    else        dst[i] = ((const bf16*)src)[i];
}

__global__ __launch_bounds__(256) void k_build_mask(const int* __restrict__ e32, int E,
                                                    const int* __restrict__ eflag,
                                                    unsigned* __restrict__ mask) {
    int e = blockIdx.x * blockDim.x + threadIdx.x;
    if (e >= E) return;
    int s, d;
    if (*eflag) { s = e32[2 * e];  d = e32[2 * E + 2 * e]; }   // int64 LE, low words
    else        { s = e32[e];      d = e32[E + e]; }           // int32
    if ((unsigned)s < N_NODES && (unsigned)d < N_NODES)
        atomicOr(&mask[s * MASK_WPR + (d >> 5)], 1u << (d & 31));
}

// C[M x N] = A[M x K] @ B[K x N], bf16 in/out, f32 accum. grid (M/64, N/16),
// 4 waves/block, wave w owns rows [bx*64+w*16, +16).
// MFMA 16x16x32 bf16 layouts (HW-verified m89):
//   A: lane l -> row l&15, k = 8*(l>>4)+j ; B: lane l -> col l&15, same k
//   D: lane l -> col l&15, row = (l>>4)*4 + reg
__global__ __launch_bounds__(256) void k_gemm(const bf16* __restrict__ A,
                                              const bf16* __restrict__ B,
                                              bf16* __restrict__ C,
                                              int K, int N) {
    int lane = threadIdx.x & 63;
    int wid  = threadIdx.x >> 6;
    int row0 = blockIdx.x * 64 + wid * 16;
    int col0 = blockIdx.y * 16;
    int r = lane & 15;
    int g = lane >> 4;
    f32x4 acc = {0.f, 0.f, 0.f, 0.f};
    for (int k0 = 0; k0 < K; k0 += 32) {
        bf16x8 a = *(const bf16x8*)(A + (size_t)(row0 + r) * K + k0 + g * 8);
        bf16x8 b;
        int kb = k0 + g * 8;
        #pragma unroll
        for (int j = 0; j < 8; ++j) b[j] = B[(size_t)(kb + j) * N + col0 + r];
        acc = __builtin_amdgcn_mfma_f32_16x16x32_bf16(a, b, acc, 0, 0, 0);
    }
    #pragma unroll
    for (int j = 0; j < 4; ++j)
        C[(size_t)(row0 + g * 4 + j) * N + col0 + r] = (bf16)acc[j];
}

// Final projection: same GEMM, but bias read + C write branch on float staging.
__global__ __launch_bounds__(256) void k_gemm_out(const bf16* __restrict__ A,
                                                  const bf16* __restrict__ B,
                                                  void* __restrict__ Cout,
                                                  const void* __restrict__ bias,
                                                  int K, int N,
                                                  const int* __restrict__ fflag) {
    int lane = threadIdx.x & 63;
    int wid  = threadIdx.x >> 6;
    int row0 = blockIdx.x * 64 + wid * 16;
    int col0 = blockIdx.y * 16;
    int r = lane & 15;
    int g = lane >> 4;
    f32x4 acc = {0.f, 0.f, 0.f, 0.f};
    for (int k0 = 0; k0 < K; k0 += 32) {
        bf16x8 a = *(const bf16x8*)(A + (size_t)(row0 + r) * K + k0 + g * 8);
        bf16x8 b;
        int kb = k0 + g * 8;
        #pragma unroll
        for (int j = 0; j < 8; ++j) b[j] = B[(size_t)(kb + j) * N + col0 + r];
        acc = __builtin_amdgcn_mfma_f32_16x16x32_bf16(a, b, acc, 0, 0, 0);
    }
    int f32io = *fflag;
    int cc = col0 + r;
    float bv = f32io ? ((const float*)bias)[cc] : (float)((const bf16*)bias)[cc];
    #pragma unroll
    for (int j = 0; j < 4; ++j) {
        int rr = row0 + g * 4 + j;
        float v = acc[j] + bv;
        if (f32io) ((float*)Cout)[(size_t)rr * N + cc] = v;
        else       ((bf16*)Cout)[(size_t)rr * N + cc] = (bf16)v;
    }
}

// One block per node (4 waves = 4 heads). Bitmask -> LDS neighbor list (dedup'd),
// then per-neighbor wave-dot via shfl_xor butterfly, exp, online sum.
__global__ __launch_bounds__(256) void k_attn(const unsigned* __restrict__ mask,
                                              const bf16* __restrict__ qb,
                                              const bf16* __restrict__ kb,
                                              const bf16* __restrict__ vb,
                                              bf16* __restrict__ ob) {
    __shared__ int s_cnt;
    __shared__ int s_list[256];
    int n = blockIdx.x;
    int t = threadIdx.x;
    if (t == 0) s_cnt = 0;
    __syncthreads();
    if (t < MASK_WPR) {
        unsigned w = mask[n * MASK_WPR + t];
        if (t == (n >> 5)) w |= 1u << (n & 31);  // self-loop always present in ref
        if (w) {
            int nb = __popc(w);
            int off = atomicAdd(&s_cnt, nb);
            int base = t << 5;
            while (w) {
                int b = __ffs(w) - 1;
                w &= w - 1;
                if (off < 256) s_list[off] = base + b;
                ++off;
            }
        }
    }
    __syncthreads();
    int cnt = min(s_cnt, 256);
    int lane = t & 63;
    int h = t >> 6;
    const bf16* qrow = qb + (size_t)n * QKV_N + h * HIDC + lane * 2;
    float q0 = (float)qrow[0], q1 = (float)qrow[1];
    float acc0 = 0.f, acc1 = 0.f, denom = 0.f;
    const float scale = 0.0883883476483184f;  // 1/sqrt(128)
    for (int i = 0; i < cnt; ++i) {
        int m = s_list[i];
        const bf16* krow = kb + (size_t)m * QKV_N + h * HIDC + lane * 2;
        float p = q0 * (float)krow[0] + q1 * (float)krow[1];
        #pragma unroll
        for (int o = 32; o; o >>= 1) p += __shfl_xor(p, o);
        float e = __expf(p * scale);
        denom += e;
        const bf16* vrow = vb + (size_t)m * QKV_N + h * HIDC + lane * 2;
        acc0 += e * (float)vrow[0];
        acc1 += e * (float)vrow[1];
    }
    float inv = (denom > 0.f) ? 1.f / denom : 0.f;
    bf16* orow = ob + (size_t)n * QKV_N + h * HIDC + lane * 2;
    orow[0] = (bf16)(acc0 * inv);
    orow[1] = (bf16)(acc1 * inv);
}

extern "C" void kernel_launch(void* const* d_in, const int* in_sizes, int n_in,
                              void* d_out, int out_size, void* d_ws, size_t ws_size,
                              hipStream_t stream) {
    const void* H    = d_in[0];
    const int* edges = (const int*)d_in[1];
    const void* Wq   = d_in[2];
    const void* Wk   = d_in[3];
    const void* Wv   = d_in[4];
    const void* Wp   = d_in[5];
    const void* bp   = d_in[6];
    int E = in_sizes[1] / 2;  // (2,E); element count is dtype-agnostic

    char* ws = (char*)d_ws;
    size_t off = 0;
    unsigned* mask = (unsigned*)(ws + off); off += (size_t)N_NODES * MASK_WPR * 4;  // 4.72 MB
    bf16* Hc  = (bf16*)(ws + off); off += (size_t)N_NODES * HIDC * 2;               // 1.57 MB
    bf16* Wqc = (bf16*)(ws + off); off += (size_t)HIDC * QKV_N * 2;
    bf16* Wkc = (bf16*)(ws + off); off += (size_t)HIDC * QKV_N * 2;
    bf16* Wvc = (bf16*)(ws + off); off += (size_t)HIDC * QKV_N * 2;
    bf16* Wpc = (bf16*)(ws + off); off += (size_t)QKV_N * HIDC * 2;
    bf16* qbuf = (bf16*)(ws + off); off += (size_t)N_NODES * QKV_N * 2;             // 6.29 MB
    bf16* kbuf = (bf16*)(ws + off); off += (size_t)N_NODES * QKV_N * 2;
    bf16* vbuf = (bf16*)(ws + off); off += (size_t)N_NODES * QKV_N * 2;
    bf16* abuf = (bf16*)(ws + off); off += (size_t)N_NODES * QKV_N * 2;
    int* eflag = (int*)(ws + off); off += 16;
    int* fflag = (int*)(ws + off); off += 16;                                       // ~32 MB total

    k_detect_f<<<1, 64, 0, stream>>>((const unsigned*)H, fflag);
    k_detect_e<<<1, 64, 0, stream>>>(edges, eflag);
    hipMemsetAsync(mask, 0, (size_t)N_NODES * MASK_WPR * 4, stream);
    k_build_mask<<<(E + 255) / 256, 256, 0, stream>>>(edges, E, eflag, mask);

    k_cast<<<(N_NODES * HIDC + 255) / 256, 256, 0, stream>>>(H, Hc, N_NODES * HIDC, fflag);
    k_cast<<<(HIDC * QKV_N + 255) / 256, 256, 0, stream>>>(Wq, Wqc, HIDC * QKV_N, fflag);
    k_cast<<<(HIDC * QKV_N + 255) / 256, 256, 0, stream>>>(Wk, Wkc, HIDC * QKV_N, fflag);
    k_cast<<<(HIDC * QKV_N + 255) / 256, 256, 0, stream>>>(Wv, Wvc, HIDC * QKV_N, fflag);
    k_cast<<<(QKV_N * HIDC + 255) / 256, 256, 0, stream>>>(Wp, Wpc, QKV_N * HIDC, fflag);

    dim3 g1(N_NODES / 64, QKV_N / 16);
    k_gemm<<<g1, 256, 0, stream>>>(Hc, Wqc, qbuf, HIDC, QKV_N);
    k_gemm<<<g1, 256, 0, stream>>>(Hc, Wkc, kbuf, HIDC, QKV_N);
    k_gemm<<<g1, 256, 0, stream>>>(Hc, Wvc, vbuf, HIDC, QKV_N);

    k_attn<<<N_NODES, 256, 0, stream>>>(mask, qbuf, kbuf, vbuf, abuf);

    dim3 g2(N_NODES / 64, HIDC / 16);
    k_gemm_out<<<g2, 256, 0, stream>>>(abuf, Wpc, d_out, bp, QKV_N, HIDC, fflag);
}

// Round 14
// 173.471 us; speedup vs baseline: 1.2663x; 1.2663x over previous
//
#include <hip/hip_runtime.h>
#include <hip/hip_bf16.h>

// MaskedGAT: N=6144, HID=128, HEADS=4. R14 optimization round (first green run
// R13: 219.7us, absmax 0.0117, fflag=1/eflag=1 confirmed).
// R13 profile: k_attn 87us (VALU 39%, 6-shfl serial chain + 4B scalar loads);
// QKV GEMMs with 8 scalar strided B-loads per MFMA; 5 cast launches.
// R14: (1) k_attn 4-neighbor-parallel: 16-lane dots, bf16x8 loads, 1 shfl
// step/neighbor amortized; (2) QKV fused into ONE GEMM vs transposed weights
// (contiguous bf16x8 B-fragments); (3) one cast+transpose kernel. 8 dispatches.

#define N_NODES 6144
#define HIDC 128
#define QKV_N 1536                // fused q|k|v row width
#define OUT_N 512                 // HEADS*HID (abuf / output-GEMM K)
#define MASK_WPR 192              // 6144/32 words per row

typedef __bf16 bf16;
typedef __attribute__((ext_vector_type(8))) __bf16 bf16x8;
typedef __attribute__((ext_vector_type(4))) float f32x4;

// fflag=1 iff floats staged f32 (verified on HW in R13: fired 1). Vote on word
// bits [14:7]: low-bf16 exponent (~[110,135] for N(0,1)) vs f32 mid-mantissa
// (uniform, ~10% in range).
__global__ void k_detect_f(const unsigned* __restrict__ Hw, int* __restrict__ fflag) {
    int lane = threadIdx.x;
    unsigned w = Hw[lane];
    int el = (w >> 7) & 0xFF;
    unsigned long long b = __ballot(el >= 110 && el <= 135);
    if (lane == 0) *fflag = (__popcll(b) >= 32) ? 0 : 1;
}

// eflag=1 iff edges staged int64 (odd 32-bit words all zero; verified R13).
__global__ void k_detect_e(const int* __restrict__ e32, int* __restrict__ eflag) {
    int lane = threadIdx.x;
    unsigned long long b = __ballot(e32[2 * lane + 1] == 0);
    if (lane == 0) *eflag = (b == ~0ull) ? 1 : 0;
}

__global__ __launch_bounds__(256) void k_build_mask(const int* __restrict__ e32, int E,
                                                    const int* __restrict__ eflag,
                                                    unsigned* __restrict__ mask) {
    int e = blockIdx.x * blockDim.x + threadIdx.x;
    if (e >= E) return;
    int s, d;
    if (*eflag) { s = e32[2 * e];  d = e32[2 * E + 2 * e]; }
    else        { s = e32[e];      d = e32[E + e]; }
    if ((unsigned)s < N_NODES && (unsigned)d < N_NODES)
        atomicOr(&mask[s * MASK_WPR + (d >> 5)], 1u << (d & 31));
}

// One kernel: cast H -> Hc (bf16), and build transposed weights:
// Wt_qkv[c][k] (c = s*512+n, s in {q,k,v}) and Wpt[n][k]. Contiguous writes,
// strided (cached) reads. Segments by blockIdx (all sizes compile-time).
__global__ __launch_bounds__(256) void k_cast_all(const void* __restrict__ H,
                                                  const void* __restrict__ Wq,
                                                  const void* __restrict__ Wk,
                                                  const void* __restrict__ Wv,
                                                  const void* __restrict__ Wp,
                                                  bf16* __restrict__ Hc,
                                                  bf16* __restrict__ Wt_qkv,
                                                  bf16* __restrict__ Wpt,
                                                  const int* __restrict__ fflag) {
    int b = blockIdx.x;
    int t = threadIdx.x;
    int f = *fflag;
    if (b < 3072) {                       // H: 786432 elems, straight cast
        int i = b * 256 + t;
        Hc[i] = f ? (bf16)((const float*)H)[i] : ((const bf16*)H)[i];
    } else if (b < 3840) {                // Wq/Wk/Wv: 3 x 65536, transpose
        int s = (b - 3072) >> 8;          // 256 blocks per matrix
        int e = ((b - 3072) & 255) * 256 + t;
        int n = e >> 7, k = e & 127;      // W[k][n], k<128, n<512
        const void* W = (s == 0) ? Wq : (s == 1) ? Wk : Wv;
        float v = f ? ((const float*)W)[k * 512 + n] : (float)((const bf16*)W)[k * 512 + n];
        Wt_qkv[(size_t)(s * 512 + n) * 128 + k] = (bf16)v;
    } else {                              // Wp: 65536, transpose [512][128]->[128][512]
        int e = (b - 3840) * 256 + t;
        int n = e >> 9, k = e & 511;      // Wp[k][n], k<512, n<128
        float v = f ? ((const float*)Wp)[k * 128 + n] : (float)((const bf16*)Wp)[k * 128 + n];
        Wpt[(size_t)n * 512 + k] = (bf16)v;
    }
}

// Fused QKV GEMM: C[6144][1536] = Hc[6144][128] @ Wt_qkv^T. Bt rows are
// contiguous in k -> B-fragment = one bf16x8 load (no scalar staging).
// grid (96, 24); wave = 16 rows x 64 cols (4 col-tiles, 4 MFMA/K-step).
// MFMA 16x16x32 layouts (HW-verified m89): A lane->row l&15,k=8*(l>>4)+j;
// B lane->col l&15 same k; D lane->col l&15,row=(l>>4)*4+reg.
__global__ __launch_bounds__(256) void k_gemm_qkv(const bf16* __restrict__ A,
                                                  const bf16* __restrict__ Bt,
                                                  bf16* __restrict__ C) {
    int lane = threadIdx.x & 63;
    int wid  = threadIdx.x >> 6;
    int row0 = blockIdx.x * 64 + wid * 16;
    int col0 = blockIdx.y * 64;
    int r = lane & 15;
    int g = lane >> 4;
    f32x4 acc[4] = {{0,0,0,0},{0,0,0,0},{0,0,0,0},{0,0,0,0}};
    for (int k0 = 0; k0 < 128; k0 += 32) {
        bf16x8 a = *(const bf16x8*)(A + (size_t)(row0 + r) * 128 + k0 + g * 8);
        #pragma unroll
        for (int ct = 0; ct < 4; ++ct) {
            bf16x8 b = *(const bf16x8*)(Bt + (size_t)(col0 + ct * 16 + r) * 128 + k0 + g * 8);
            acc[ct] = __builtin_amdgcn_mfma_f32_16x16x32_bf16(a, b, acc[ct], 0, 0, 0);
        }
    }
    #pragma unroll
    for (int ct = 0; ct < 4; ++ct)
        #pragma unroll
        for (int j = 0; j < 4; ++j)
            C[(size_t)(row0 + g * 4 + j) * QKV_N + col0 + ct * 16 + r] = (bf16)acc[ct][j];
}

// Attention: block = node, wave = head. 4 neighbors processed in parallel
// (lane = g*16+r: group g owns neighbor i0+g, lane covers dims [8r,8r+8) via
// one bf16x8 load). Dot reduced over 16 lanes (4 shfl steps for 4 neighbors
// at once = 1 step/neighbor amortized, vs 6/neighbor in R13). Group partials
// merged once at the end (2 shfl per value).
__global__ __launch_bounds__(256) void k_attn(const unsigned* __restrict__ mask,
                                              const bf16* __restrict__ qkv,
                                              bf16* __restrict__ ob) {
    __shared__ int s_cnt;
    __shared__ int s_list[256];
    int n = blockIdx.x;
    int t = threadIdx.x;
    if (t == 0) s_cnt = 0;
    __syncthreads();
    if (t < MASK_WPR) {
        unsigned w = mask[n * MASK_WPR + t];
        if (t == (n >> 5)) w |= 1u << (n & 31);  // self-loop always present in ref
        if (w) {
            int nb = __popc(w);
            int off = atomicAdd(&s_cnt, nb);
            int base = t << 5;
            while (w) {
                int b = __ffs(w) - 1;
                w &= w - 1;
                if (off < 256) s_list[off] = base + b;
                ++off;
            }
        }
    }
    __syncthreads();
    int cnt = min(s_cnt, 256);
    int lane = t & 63;
    int h = t >> 6;
    int g = lane >> 4;
    int r = lane & 15;
    bf16x8 qv = *(const bf16x8*)(qkv + (size_t)n * QKV_N + h * HIDC + r * 8);
    float qf[8];
    #pragma unroll
    for (int j = 0; j < 8; ++j) qf[j] = (float)qv[j];
    float acc[8] = {0, 0, 0, 0, 0, 0, 0, 0};
    float denom = 0.f;
    const float scale = 0.0883883476483184f;  // 1/sqrt(128)
    for (int i0 = 0; i0 < cnt; i0 += 4) {
        int idx = i0 + g;
        bool act = idx < cnt;
        int m = s_list[act ? idx : 0];       // safe row; e=0 kills inactive
        const bf16* kr = qkv + (size_t)m * QKV_N + 512 + h * HIDC + r * 8;
        bf16x8 kv = *(const bf16x8*)kr;
        float p = 0.f;
        #pragma unroll
        for (int j = 0; j < 8; ++j) p += qf[j] * (float)kv[j];
        p += __shfl_xor(p, 1);
        p += __shfl_xor(p, 2);
        p += __shfl_xor(p, 4);
        p += __shfl_xor(p, 8);               // stays within 16-lane group
        float e = act ? __expf(p * scale) : 0.f;
        denom += e;
        const bf16* vr = qkv + (size_t)m * QKV_N + 1024 + h * HIDC + r * 8;
        bf16x8 vv = *(const bf16x8*)vr;
        #pragma unroll
        for (int j = 0; j < 8; ++j) acc[j] += e * (float)vv[j];
    }
    denom += __shfl_xor(denom, 16);
    denom += __shfl_xor(denom, 32);
    #pragma unroll
    for (int j = 0; j < 8; ++j) {
        acc[j] += __shfl_xor(acc[j], 16);
        acc[j] += __shfl_xor(acc[j], 32);
    }
    if (lane < 16) {
        float inv = (denom > 0.f) ? 1.f / denom : 0.f;
        bf16x8 o;
        #pragma unroll
        for (int j = 0; j < 8; ++j) o[j] = (bf16)(acc[j] * inv);
        *(bf16x8*)(ob + (size_t)n * OUT_N + h * HIDC + r * 8) = o;
    }
}

// Output projection: [6144][128] = abuf[6144][512] @ Wpt^T + bp; f32/bf16 out
// per fflag. grid (96, 8); wave = 16x16, 16 MFMA over K=512.
__global__ __launch_bounds__(256) void k_gemm_out(const bf16* __restrict__ A,
                                                  const bf16* __restrict__ Bt,
                                                  void* __restrict__ Cout,
                                                  const void* __restrict__ bias,
                                                  const int* __restrict__ fflag) {
    int lane = threadIdx.x & 63;
    int wid  = threadIdx.x >> 6;
    int row0 = blockIdx.x * 64 + wid * 16;
    int col0 = blockIdx.y * 16;
    int r = lane & 15;
    int g = lane >> 4;
    f32x4 acc = {0.f, 0.f, 0.f, 0.f};
    for (int k0 = 0; k0 < OUT_N; k0 += 32) {
        bf16x8 a = *(const bf16x8*)(A + (size_t)(row0 + r) * OUT_N + k0 + g * 8);
        bf16x8 b = *(const bf16x8*)(Bt + (size_t)(col0 + r) * OUT_N + k0 + g * 8);
        acc = __builtin_amdgcn_mfma_f32_16x16x32_bf16(a, b, acc, 0, 0, 0);
    }
    int f32io = *fflag;
    int cc = col0 + r;
    float bv = f32io ? ((const float*)bias)[cc] : (float)((const bf16*)bias)[cc];
    #pragma unroll
    for (int j = 0; j < 4; ++j) {
        int rr = row0 + g * 4 + j;
        float v = acc[j] + bv;
        if (f32io) ((float*)Cout)[(size_t)rr * HIDC + cc] = v;
        else       ((bf16*)Cout)[(size_t)rr * HIDC + cc] = (bf16)v;
    }
}

extern "C" void kernel_launch(void* const* d_in, const int* in_sizes, int n_in,
                              void* d_out, int out_size, void* d_ws, size_t ws_size,
                              hipStream_t stream) {
    const void* H    = d_in[0];
    const int* edges = (const int*)d_in[1];
    const void* Wq   = d_in[2];
    const void* Wk   = d_in[3];
    const void* Wv   = d_in[4];
    const void* Wp   = d_in[5];
    const void* bp   = d_in[6];
    int E = in_sizes[1] / 2;

    char* ws = (char*)d_ws;
    size_t off = 0;
    unsigned* mask  = (unsigned*)(ws + off); off += (size_t)N_NODES * MASK_WPR * 4;   // 4.72 MB
    bf16* Hc        = (bf16*)(ws + off);     off += (size_t)N_NODES * HIDC * 2;       // 1.57 MB
    bf16* Wt_qkv    = (bf16*)(ws + off);     off += (size_t)QKV_N * HIDC * 2;         // 0.39 MB
    bf16* Wpt       = (bf16*)(ws + off);     off += (size_t)HIDC * OUT_N * 2;         // 0.13 MB
    bf16* qkvbuf    = (bf16*)(ws + off);     off += (size_t)N_NODES * QKV_N * 2;      // 18.9 MB
    bf16* abuf      = (bf16*)(ws + off);     off += (size_t)N_NODES * OUT_N * 2;      // 6.29 MB
    int* eflag      = (int*)(ws + off);      off += 16;
    int* fflag      = (int*)(ws + off);      off += 16;                               // ~32 MB

    k_detect_f<<<1, 64, 0, stream>>>((const unsigned*)H, fflag);
    k_detect_e<<<1, 64, 0, stream>>>(edges, eflag);
    hipMemsetAsync(mask, 0, (size_t)N_NODES * MASK_WPR * 4, stream);
    k_build_mask<<<(E + 255) / 256, 256, 0, stream>>>(edges, E, eflag, mask);

    k_cast_all<<<4096, 256, 0, stream>>>(H, Wq, Wk, Wv, Wp, Hc, Wt_qkv, Wpt, fflag);

    dim3 g1(N_NODES / 64, QKV_N / 64);   // (96, 24)
    k_gemm_qkv<<<g1, 256, 0, stream>>>(Hc, Wt_qkv, qkvbuf);

    k_attn<<<N_NODES, 256, 0, stream>>>(mask, qkvbuf, abuf);

    dim3 g2(N_NODES / 64, HIDC / 16);    // (96, 8)
    k_gemm_out<<<g2, 256, 0, stream>>>(abuf, Wpt, d_out, bp, fflag);
}

// Round 15
// 170.807 us; speedup vs baseline: 1.2860x; 1.0156x over previous
//
#include <hip/hip_runtime.h>
#include <hip/hip_bf16.h>

// MaskedGAT: N=6144, HID=128, HEADS=4. R15.
// R14 profile: k_attn 48us = latency-bound gather (147MB L2-miss @3.3TB/s, VALU
// 42%, only 2 loads in flight per iter); k_gemm_out re-reads abuf 8x; 8 dispatches.
// R15: (1) attn 8-neighbor unroll (2 independent slots -> 2x MLP, interleaved
// shfl chains); (2) gemm_out 64-wide col tiles (A-traffic 4x down); (3) detects
// merged into one 2-wave kernel. Dtype flags (f32 floats / int64 edges) verified
// on HW in R13/R14.

#define N_NODES 6144
#define HIDC 128
#define QKV_N 1536                // fused q|k|v row width
#define OUT_N 512                 // HEADS*HID (abuf / output-GEMM K)
#define MASK_WPR 192              // 6144/32 words per row

typedef __bf16 bf16;
typedef __attribute__((ext_vector_type(8))) __bf16 bf16x8;
typedef __attribute__((ext_vector_type(4))) float f32x4;

// Wave 0: fflag=1 iff floats staged f32 (bits[14:7] = low-bf16 exponent test;
// fired 1 on HW). Wave 1: eflag=1 iff edges staged int64 (odd words zero).
__global__ void k_detect(const unsigned* __restrict__ Hw, const int* __restrict__ e32,
                         int* __restrict__ fflag, int* __restrict__ eflag) {
    int w = threadIdx.x >> 6, lane = threadIdx.x & 63;
    if (w == 0) {
        unsigned x = Hw[lane];
        int el = (x >> 7) & 0xFF;
        unsigned long long b = __ballot(el >= 110 && el <= 135);
        if (lane == 0) *fflag = (__popcll(b) >= 32) ? 0 : 1;
    } else {
        unsigned long long b = __ballot(e32[2 * lane + 1] == 0);
        if (lane == 0) *eflag = (b == ~0ull) ? 1 : 0;
    }
}

__global__ __launch_bounds__(256) void k_build_mask(const int* __restrict__ e32, int E,
                                                    const int* __restrict__ eflag,
                                                    unsigned* __restrict__ mask) {
    int e = blockIdx.x * blockDim.x + threadIdx.x;
    if (e >= E) return;
    int s, d;
    if (*eflag) { s = e32[2 * e];  d = e32[2 * E + 2 * e]; }
    else        { s = e32[e];      d = e32[E + e]; }
    if ((unsigned)s < N_NODES && (unsigned)d < N_NODES)
        atomicOr(&mask[s * MASK_WPR + (d >> 5)], 1u << (d & 31));
}

// Cast H -> bf16, transpose+cast Wq|Wk|Wv -> Wt_qkv[c][k], Wp -> Wpt[n][k].
__global__ __launch_bounds__(256) void k_cast_all(const void* __restrict__ H,
                                                  const void* __restrict__ Wq,
                                                  const void* __restrict__ Wk,
                                                  const void* __restrict__ Wv,
                                                  const void* __restrict__ Wp,
                                                  bf16* __restrict__ Hc,
                                                  bf16* __restrict__ Wt_qkv,
                                                  bf16* __restrict__ Wpt,
                                                  const int* __restrict__ fflag) {
    int b = blockIdx.x;
    int t = threadIdx.x;
    int f = *fflag;
    if (b < 3072) {                       // H: 786432 elems
        int i = b * 256 + t;
        Hc[i] = f ? (bf16)((const float*)H)[i] : ((const bf16*)H)[i];
    } else if (b < 3840) {                // Wq/Wk/Wv: 3 x 65536, transpose
        int s = (b - 3072) >> 8;
        int e = ((b - 3072) & 255) * 256 + t;
        int n = e >> 7, k = e & 127;      // W[k][n], k<128, n<512
        const void* W = (s == 0) ? Wq : (s == 1) ? Wk : Wv;
        float v = f ? ((const float*)W)[k * 512 + n] : (float)((const bf16*)W)[k * 512 + n];
        Wt_qkv[(size_t)(s * 512 + n) * 128 + k] = (bf16)v;
    } else {                              // Wp: [512][128] -> Wpt[128][512]
        int e = (b - 3840) * 256 + t;
        int n = e >> 9, k = e & 511;
        float v = f ? ((const float*)Wp)[k * 128 + n] : (float)((const bf16*)Wp)[k * 128 + n];
        Wpt[(size_t)n * 512 + k] = (bf16)v;
    }
}

// Fused QKV GEMM: C[6144][1536] = Hc @ Wt_qkv^T. grid (96,24); wave = 16 rows
// x 64 cols. MFMA 16x16x32 layouts (m89): A lane->row l&15, k=8*(l>>4)+j;
// B lane->col l&15 same k; D lane->col l&15, row=(l>>4)*4+reg.
__global__ __launch_bounds__(256) void k_gemm_qkv(const bf16* __restrict__ A,
                                                  const bf16* __restrict__ Bt,
                                                  bf16* __restrict__ C) {
    int lane = threadIdx.x & 63;
    int wid  = threadIdx.x >> 6;
    int row0 = blockIdx.x * 64 + wid * 16;
    int col0 = blockIdx.y * 64;
    int r = lane & 15;
    int g = lane >> 4;
    f32x4 acc[4] = {{0,0,0,0},{0,0,0,0},{0,0,0,0},{0,0,0,0}};
    for (int k0 = 0; k0 < 128; k0 += 32) {
        bf16x8 a = *(const bf16x8*)(A + (size_t)(row0 + r) * 128 + k0 + g * 8);
        #pragma unroll
        for (int ct = 0; ct < 4; ++ct) {
            bf16x8 b = *(const bf16x8*)(Bt + (size_t)(col0 + ct * 16 + r) * 128 + k0 + g * 8);
            acc[ct] = __builtin_amdgcn_mfma_f32_16x16x32_bf16(a, b, acc[ct], 0, 0, 0);
        }
    }
    #pragma unroll
    for (int ct = 0; ct < 4; ++ct)
        #pragma unroll
        for (int j = 0; j < 4; ++j)
            C[(size_t)(row0 + g * 4 + j) * QKV_N + col0 + ct * 16 + r] = (bf16)acc[ct][j];
}

// Attention: block = node, wave = head. 8 neighbors per iteration in TWO
// independent 4-slots (A,B): both K loads issued before either dot, both V
// loads before accumulation -> 2x memory-level parallelism vs R14 (the R14
// profile showed latency-bound gather: 3.3TB/s, VALU 42%, no pipe saturated).
__global__ __launch_bounds__(256) void k_attn(const unsigned* __restrict__ mask,
                                              const bf16* __restrict__ qkv,
                                              bf16* __restrict__ ob) {
    __shared__ int s_cnt;
    __shared__ int s_list[256];
    int n = blockIdx.x;
    int t = threadIdx.x;
    if (t == 0) s_cnt = 0;
    __syncthreads();
    if (t < MASK_WPR) {
        unsigned w = mask[n * MASK_WPR + t];
        if (t == (n >> 5)) w |= 1u << (n & 31);  // self-loop always present in ref
        if (w) {
            int nb = __popc(w);
            int off = atomicAdd(&s_cnt, nb);
            int base = t << 5;
            while (w) {
                int b = __ffs(w) - 1;
                w &= w - 1;
                if (off < 256) s_list[off] = base + b;
                ++off;
            }
        }
    }
    __syncthreads();
    int cnt = min(s_cnt, 256);
    int lane = t & 63;
    int h = t >> 6;
    int g = lane >> 4;
    int r = lane & 15;
    bf16x8 qv = *(const bf16x8*)(qkv + (size_t)n * QKV_N + h * HIDC + r * 8);
    float qf[8];
    #pragma unroll
    for (int j = 0; j < 8; ++j) qf[j] = (float)qv[j];
    float accA[8] = {0,0,0,0,0,0,0,0}, accB[8] = {0,0,0,0,0,0,0,0};
    float denA = 0.f, denB = 0.f;
    const float scale = 0.0883883476483184f;  // 1/sqrt(128)
    for (int i0 = 0; i0 < cnt; i0 += 8) {
        int iA = i0 + g, iB = i0 + 4 + g;
        bool aA = iA < cnt, aB = iB < cnt;
        int mA = s_list[aA ? iA : 0];
        int mB = s_list[aB ? iB : 0];
        const bf16* baseA = qkv + (size_t)mA * QKV_N + 512 + h * HIDC + r * 8;
        const bf16* baseB = qkv + (size_t)mB * QKV_N + 512 + h * HIDC + r * 8;
        bf16x8 kA = *(const bf16x8*)baseA;           // both K loads in flight
        bf16x8 kB = *(const bf16x8*)baseB;
        float pA = 0.f, pB = 0.f;
        #pragma unroll
        for (int j = 0; j < 8; ++j) { pA += qf[j] * (float)kA[j]; pB += qf[j] * (float)kB[j]; }
        #pragma unroll
        for (int o = 1; o <= 8; o <<= 1) {           // two interleaved shfl chains
            pA += __shfl_xor(pA, o);
            pB += __shfl_xor(pB, o);
        }
        float eA = aA ? __expf(pA * scale) : 0.f;
        float eB = aB ? __expf(pB * scale) : 0.f;
        denA += eA; denB += eB;
        bf16x8 vA = *(const bf16x8*)(baseA + 512);   // both V loads in flight
        bf16x8 vB = *(const bf16x8*)(baseB + 512);
        #pragma unroll
        for (int j = 0; j < 8; ++j) { accA[j] += eA * (float)vA[j]; accB[j] += eB * (float)vB[j]; }
    }
    float denom = denA + denB;
    denom += __shfl_xor(denom, 16);
    denom += __shfl_xor(denom, 32);
    float acc[8];
    #pragma unroll
    for (int j = 0; j < 8; ++j) {
        acc[j] = accA[j] + accB[j];
        acc[j] += __shfl_xor(acc[j], 16);
        acc[j] += __shfl_xor(acc[j], 32);
    }
    if (lane < 16) {
        float inv = (denom > 0.f) ? 1.f / denom : 0.f;
        bf16x8 o;
        #pragma unroll
        for (int j = 0; j < 8; ++j) o[j] = (bf16)(acc[j] * inv);
        *(bf16x8*)(ob + (size_t)n * OUT_N + h * HIDC + r * 8) = o;
    }
}

// Output projection: [6144][128] = abuf[6144][512] @ Wpt^T + bp. grid (96,2);
// wave = 16 rows x 64 cols (4 col-tiles) -> abuf re-read 2x instead of 8x.
__global__ __launch_bounds__(256) void k_gemm_out(const bf16* __restrict__ A,
                                                  const bf16* __restrict__ Bt,
                                                  void* __restrict__ Cout,
                                                  const void* __restrict__ bias,
                                                  const int* __restrict__ fflag) {
    int lane = threadIdx.x & 63;
    int wid  = threadIdx.x >> 6;
    int row0 = blockIdx.x * 64 + wid * 16;
    int col0 = blockIdx.y * 64;
    int r = lane & 15;
    int g = lane >> 4;
    f32x4 acc[4] = {{0,0,0,0},{0,0,0,0},{0,0,0,0},{0,0,0,0}};
    for (int k0 = 0; k0 < OUT_N; k0 += 32) {
        bf16x8 a = *(const bf16x8*)(A + (size_t)(row0 + r) * OUT_N + k0 + g * 8);
        #pragma unroll
        for (int ct = 0; ct < 4; ++ct) {
            bf16x8 b = *(const bf16x8*)(Bt + (size_t)(col0 + ct * 16 + r) * OUT_N + k0 + g * 8);
            acc[ct] = __builtin_amdgcn_mfma_f32_16x16x32_bf16(a, b, acc[ct], 0, 0, 0);
        }
    }
    int f32io = *fflag;
    #pragma unroll
    for (int ct = 0; ct < 4; ++ct) {
        int cc = col0 + ct * 16 + r;
        float bv = f32io ? ((const float*)bias)[cc] : (float)((const bf16*)bias)[cc];
        #pragma unroll
        for (int j = 0; j < 4; ++j) {
            int rr = row0 + g * 4 + j;
            float v = acc[ct][j] + bv;
            if (f32io) ((float*)Cout)[(size_t)rr * HIDC + cc] = v;
            else       ((bf16*)Cout)[(size_t)rr * HIDC + cc] = (bf16)v;
        }
    }
}

extern "C" void kernel_launch(void* const* d_in, const int* in_sizes, int n_in,
                              void* d_out, int out_size, void* d_ws, size_t ws_size,
                              hipStream_t stream) {
    const void* H    = d_in[0];
    const int* edges = (const int*)d_in[1];
    const void* Wq   = d_in[2];
    const void* Wk   = d_in[3];
    const void* Wv   = d_in[4];
    const void* Wp   = d_in[5];
    const void* bp   = d_in[6];
    int E = in_sizes[1] / 2;

    char* ws = (char*)d_ws;
    size_t off = 0;
    unsigned* mask  = (unsigned*)(ws + off); off += (size_t)N_NODES * MASK_WPR * 4;   // 4.72 MB
    bf16* Hc        = (bf16*)(ws + off);     off += (size_t)N_NODES * HIDC * 2;       // 1.57 MB
    bf16* Wt_qkv    = (bf16*)(ws + off);     off += (size_t)QKV_N * HIDC * 2;         // 0.39 MB
    bf16* Wpt       = (bf16*)(ws + off);     off += (size_t)HIDC * OUT_N * 2;         // 0.13 MB
    bf16* qkvbuf    = (bf16*)(ws + off);     off += (size_t)N_NODES * QKV_N * 2;      // 18.9 MB
    bf16* abuf      = (bf16*)(ws + off);     off += (size_t)N_NODES * OUT_N * 2;      // 6.29 MB
    int* eflag      = (int*)(ws + off);      off += 16;
    int* fflag      = (int*)(ws + off);      off += 16;                               // ~32 MB

    k_detect<<<1, 128, 0, stream>>>((const unsigned*)H, edges, fflag, eflag);
    hipMemsetAsync(mask, 0, (size_t)N_NODES * MASK_WPR * 4, stream);
    k_build_mask<<<(E + 255) / 256, 256, 0, stream>>>(edges, E, eflag, mask);

    k_cast_all<<<4096, 256, 0, stream>>>(H, Wq, Wk, Wv, Wp, Hc, Wt_qkv, Wpt, fflag);

    dim3 g1(N_NODES / 64, QKV_N / 64);   // (96, 24)
    k_gemm_qkv<<<g1, 256, 0, stream>>>(Hc, Wt_qkv, qkvbuf);

    k_attn<<<N_NODES, 256, 0, stream>>>(mask, qkvbuf, abuf);

    dim3 g2(N_NODES / 64, HIDC / 64);    // (96, 2)
    k_gemm_out<<<g2, 256, 0, stream>>>(abuf, Wpt, d_out, bp, fflag);
}